// Round 14
// baseline (301.292 us; speedup 1.0000x reference)
//
#include <hip/hip_runtime.h>
#include <hip/hip_cooperative_groups.h>
#include <math.h>

// MultiBoxLoss: B=64, P=16800, G=32, C=2. SINGLE cooperative kernel, 3 phases:
//  P1: per-gt best-prior argmax (8 gts/block) + per-prior threshold bitmask
//  P2: per-prior conf+losses from bitmask (g-loop deleted, r12 ablation)
//  P3: per-batch exact top-k via 4-way bisection + last-block fold.
// grid.sync() between phases (256 blocks x 1024 thr = 1 block/CU, co-resident).

namespace cg = cooperative_groups;
#define RCP(x) __builtin_amdgcn_rcpf(x)
typedef unsigned long long u64;

constexpr int GN = 32;
constexpr int PACKF = 576;
constexpr int NCH  = 4;      // gt chunks / prior segments per batch
constexpr int GPB  = 8;      // gts per chunk
constexpr int SEG  = 4224;   // prior segment size (64-aligned); last seg 4128
constexpr int NW64A = 264;   // mask words per (batch, chunk)
constexpr int NT   = 1024;
constexpr int NWV  = NT / 64;

__device__ __forceinline__ float sl1(float x) {
    float a = fabsf(x);
    return a < 1.f ? 0.5f * a * a : a - 0.5f;
}

__global__ __launch_bounds__(NT)
void k_fused(const float2* __restrict__ cls, const float4* __restrict__ loc,
             const float* __restrict__ lmd, const float4* __restrict__ priors,
             const float* __restrict__ targets,
             u64* __restrict__ keys, float* __restrict__ pack, u64* __restrict__ wmask,
             float* __restrict__ bc, float* __restrict__ part, float* __restrict__ part2,
             float* __restrict__ out, int* __restrict__ done, int P, int B) {
    cg::grid_group grid = cg::this_grid();
    const int cb = blockIdx.x, tid = threadIdx.x;
    const int lane = tid & 63, w = tid >> 6;
    const int b = cb >> 2, sub = cb & 3;

    __shared__ float4 s_box[GPB];
    __shared__ float  s_at[GPB];
    __shared__ u64    s_wk[NWV][GPB];
    __shared__ int    s_fg[SEG];
    __shared__ unsigned s_fvb[SEG / 32];
    __shared__ unsigned s_vm;
    __shared__ float  s_red[NWV][8];
    __shared__ float  s_r[5];
    __shared__ u64    s_cw[NWV];
    __shared__ u64    s_ct;
    __shared__ float  s_rf[NWV][2];
    __shared__ float  s_ts2[2];
    __shared__ int    s_last;

    // ================= PHASE 1: gt argmax + threshold bitmask =================
    if (cb == 0 && tid == 0) *done = 0;
    const int g0 = sub * GPB;
    if (tid < GPB) {
        const float* t = targets + ((size_t)b * GN + g0 + tid) * 15;
        float4 v = make_float4(t[0], t[1], t[2], t[3]);
        float at = (v.z - v.x) * (v.w - v.y);
        s_box[tid] = v; s_at[tid] = at;
        float* pkw = pack + (size_t)b * PACKF;
        ((float4*)pkw)[g0 + tid] = v;
        pkw[128 + g0 + tid] = 0.35f * at;
        pkw[160 + g0 + tid] = at;
        pkw[192 + g0 + tid] = t[14];
    }
    {
        int q = tid - GPB;
        if (q >= 0 && q < GPB * 10) {
            int gg = g0 + q / 10, j = q % 10;
            pack[(size_t)b * PACKF + 224 + gg * 10 + j] =
                targets[((size_t)b * GN + gg) * 15 + 4 + j];
        }
    }
    __syncthreads();
    float4 tb[GPB]; float at_[GPB], c35_[GPB];
    #pragma unroll
    for (int j = 0; j < GPB; ++j) {
        tb[j] = s_box[j]; at_[j] = s_at[j]; c35_[j] = 0.35f * s_at[j];
    }
    float bv[GPB]; int bp[GPB];
    #pragma unroll
    for (int j = 0; j < GPB; ++j) { bv[j] = -1.f; bp[j] = 0; }

    u64* __restrict__ wm = wmask + ((size_t)b * NCH + sub) * NW64A;
    for (int p = tid; p < P; p += NT) {      // ascending p: '>' keeps smallest p
        float4 pr = priors[p];
        float hx = pr.z * 0.5f, hy = pr.w * 0.5f;
        float px0 = pr.x - hx, py0 = pr.y - hy;
        float px1 = pr.x + hx, py1 = pr.y + hy;
        float ap = (px1 - px0) * (py1 - py0);
        float ap35 = 0.35f * ap;
        bool pa = false;
        #pragma unroll
        for (int j = 0; j < GPB; ++j) {
            float lx = fmaxf(tb[j].x, px0), ly = fmaxf(tb[j].y, py0);
            float rx = fminf(tb[j].z, px1), ry = fminf(tb[j].w, py1);
            float iw = fmaxf(rx - lx, 0.f), ih = fmaxf(ry - ly, 0.f);
            float inter = iw * ih;
            pa = pa || (fmaf(1.35f, inter, -c35_[j]) >= ap35);   // iou >= 0.35
            float iou = inter * RCP(at_[j] + ap - inter);
            if (iou > bv[j]) { bv[j] = iou; bp[j] = p; }
        }
        u64 bal = __ballot(pa);
        if (lane == 0) wm[p >> 6] = bal;
    }
    #pragma unroll
    for (int j = 0; j < GPB; ++j) {
        u64 key = ((u64)__float_as_uint(bv[j]) << 32) | ~(unsigned)bp[j];
        #pragma unroll
        for (int o = 32; o > 0; o >>= 1) {
            u64 t = __shfl_down(key, o, 64);
            if (t > key) key = t;
        }
        if (lane == 0) s_wk[w][j] = key;
    }
    __syncthreads();
    if (tid < GPB) {
        u64 m = 0ull;
        #pragma unroll
        for (int q = 0; q < NWV; ++q) { u64 t = s_wk[q][tid]; if (t > m) m = t; }
        keys[b * GN + g0 + tid] = m;
    }
    __threadfence();
    grid.sync();

    // ================= PHASE 2: per-prior conf + losses =================
    const int base = sub * SEG;
    const int segsz = min(SEG, P - base);
    for (int i = tid; i < SEG; i += NT) s_fg[i] = -1;
    if (tid < SEG / 32) s_fvb[tid] = 0u;
    __syncthreads();
    if (tid < GN) {                                   // forced-match scatter
        u64 key = keys[b * GN + tid];
        unsigned bpz = ~(unsigned)key;
        bool val = __uint_as_float((unsigned)(key >> 32)) >= 0.2f;
        u64 bal = __ballot(val);
        if (tid == 0) s_vm = (unsigned)bal;
        int local = (int)bpz - base;
        if (local >= 0 && local < segsz) {
            atomicMax(&s_fg[local], tid);             // largest g wins
            if (val) atomicOr(&s_fvb[local >> 5], 1u << (local & 31));
        }
    }
    __syncthreads();
    const bool av = s_vm != 0u;
    const float* __restrict__ pk = pack + (size_t)b * PACKF;
    const float4* __restrict__ gbox = (const float4*)pk;
    const float* __restrict__ garea = pk + 160;
    const float* __restrict__ glab = pk + 192;
    const float* __restrict__ glm  = pk + 224;

    float a_ll = 0.f, a_lm = 0.f, a_lcp = 0.f;
    int npw = 0, np1w = 0;
    #pragma unroll
    for (int i = 0; i < 5; ++i) {                     // ceil(4224/1024)=5
        int pl = i * NT + tid;
        bool act = pl < segsz;
        int gp = base + pl;
        float2 c = act ? cls[(size_t)b * P + gp] : make_float2(0.f, 0.f);
        u64 m = 0ull;
        if (act) {
            int word = gp >> 6;                       // wave-uniform (base 64-aligned)
            #pragma unroll
            for (int ch = 0; ch < NCH; ++ch)
                m |= wmask[((size_t)b * NCH + ch) * NW64A + word];
        }
        bool thr = act && ((m >> (gp & 63)) & 1ull);
        int fidx = -1; bool fv = false;
        if (act) {
            fidx = s_fg[pl];
            fv = (s_fvb[pl >> 5] >> (pl & 31)) & 1u;
        }
        bool pos = act && av && (fv || thr);
        float lse = 0.f, d = 0.f;
        if (act) {
            d = c.y - c.x;
            float m0 = fmaxf(d, 0.f);
            lse = m0 + __logf(__expf(-m0) + __expf(d - m0));   // logz - c.x >= 0
            bc[(size_t)b * P + gp] = pos ? 0.f : lse;
        }
        if (pos) {
            npw++;
            a_lcp += lse - d;                         // logz - c.y
            float4 pr = priors[gp];
            float hx = pr.z * 0.5f, hy = pr.w * 0.5f;
            float px0 = pr.x - hx, py0 = pr.y - hy;
            float px1 = pr.x + hx, py1 = pr.y + hy;
            float ap = (px1 - px0) * (py1 - py0);
            int bti2 = fidx;
            if (fidx < 0) {                           // rare: full first-g argmax
                float btv = -1.f;
                #pragma unroll 1
                for (int g = 0; g < GN; ++g) {
                    float4 tbx = gbox[g];
                    float lx = fmaxf(tbx.x, px0), ly = fmaxf(tbx.y, py0);
                    float rx = fminf(tbx.z, px1), ry = fminf(tbx.w, py1);
                    float iw = fmaxf(rx - lx, 0.f), ih = fmaxf(ry - ly, 0.f);
                    float inter = iw * ih;
                    float iou = inter * RCP(garea[g] + ap - inter);
                    if (iou > btv) { btv = iou; bti2 = g; }
                }
            }
            float4 tbx = gbox[bti2];
            float rw = RCP(pr.z), rh = RCP(pr.w);
            float e0 = ((tbx.x + tbx.z) * 0.5f - pr.x) * rw * 10.f;
            float e1 = ((tbx.y + tbx.w) * 0.5f - pr.y) * rh * 10.f;
            float e2 = __logf((tbx.z - tbx.x) * rw) * 5.f;
            float e3 = __logf((tbx.w - tbx.y) * rh) * 5.f;
            float4 ld = loc[(size_t)b * P + gp];
            a_ll += sl1(ld.x - e0) + sl1(ld.y - e1) + sl1(ld.z - e2) + sl1(ld.w - e3);
            if (glab[bti2] > 0.f) {                   // conf > 0
                np1w++;
                const float* lp = lmd + ((size_t)b * P + gp) * 10;
                #pragma unroll
                for (int q = 0; q < 5; ++q) {
                    float gx = (glm[bti2 * 10 + 2 * q]     - pr.x) * rw * 10.f;
                    float gy = (glm[bti2 * 10 + 2 * q + 1] - pr.y) * rh * 10.f;
                    a_lm += sl1(lp[2 * q] - gx) + sl1(lp[2 * q + 1] - gy);
                }
            }
        }
    }
    {
        float a_np = (float)npw, a_np1 = (float)np1w;
        #pragma unroll
        for (int o = 32; o > 0; o >>= 1) {
            a_ll  += __shfl_down(a_ll,  o, 64);
            a_lm  += __shfl_down(a_lm,  o, 64);
            a_lcp += __shfl_down(a_lcp, o, 64);
            a_np  += __shfl_down(a_np,  o, 64);
            a_np1 += __shfl_down(a_np1, o, 64);
        }
        if (lane == 0) {
            s_red[w][0] = a_ll; s_red[w][1] = a_lm; s_red[w][2] = a_lcp;
            s_red[w][3] = a_np; s_red[w][4] = a_np1;
        }
    }
    __syncthreads();
    if (tid == 0) {
        float* pp = part + ((size_t)b * NCH + sub) * 8;
        #pragma unroll
        for (int j = 0; j < 5; ++j) {
            float s = 0.f;
            #pragma unroll
            for (int q = 0; q < NWV; ++q) s += s_red[q][j];
            pp[j] = s;
        }
    }
    __threadfence();
    grid.sync();

    // ================= PHASE 3: per-batch exact top-k + fold =================
    if (cb >= B) return;
    const int b3 = cb;
    unsigned ul[17];
    #pragma unroll
    for (int i = 0; i < 17; ++i) {
        int idx = i * NT + tid;
        ul[i] = idx < P ? __float_as_uint(bc[(size_t)b3 * P + idx]) : 0u;
    }
    if (tid < 5) {
        float s = 0.f;
        #pragma unroll
        for (int sg = 0; sg < NCH; ++sg) s += part[((size_t)b3 * NCH + sg) * 8 + tid];
        s_r[tid] = s;
    }
    __syncthreads();
    const float t_ll = s_r[0], t_lm = s_r[1], t_lcp = s_r[2];
    const float t_np = s_r[3], t_np1 = s_r[4];
    int k = (int)(t_np + 0.5f) * 7;
    if (k > P - 1) k = P - 1;

    float topk = 0.f;
    if (k > 0) {
        unsigned lo = 0u, hi = 0x7f800000u;           // finite non-negative values
        while (lo < hi) {                             // ~15 rounds (4-way)
            unsigned span = hi - lo;
            unsigned m1 = lo + ((span + 3) >> 2);
            unsigned m2 = lo + ((span + 1) >> 1);
            unsigned m3 = hi - (span >> 2);
            int c1 = 0, c2 = 0, c3 = 0;
            #pragma unroll
            for (int i = 0; i < 17; ++i) {
                unsigned u = ul[i];
                c1 += u >= m1 ? 1 : 0;
                c2 += u >= m2 ? 1 : 0;
                c3 += u >= m3 ? 1 : 0;
            }
            u64 pkk = (u64)c1 | ((u64)c2 << 20) | ((u64)c3 << 40);
            #pragma unroll
            for (int o = 32; o > 0; o >>= 1) pkk += __shfl_down(pkk, o, 64);
            if (lane == 0) s_cw[w] = pkk;
            __syncthreads();
            if (w == 0) {
                u64 t = (lane < NWV) ? s_cw[lane] : 0ull;
                #pragma unroll
                for (int o = 8; o > 0; o >>= 1) t += __shfl_down(t, o, 64);
                if (lane == 0) s_ct = t;
            }
            __syncthreads();
            u64 t = s_ct;
            int C1 = (int)(t & 0xFFFFFu);
            int C2 = (int)((t >> 20) & 0xFFFFFu);
            int C3 = (int)((t >> 40) & 0xFFFFFu);
            if      (C3 >= k) lo = m3;
            else if (C2 >= k) { lo = m2; hi = m3 - 1; }
            else if (C1 >= k) { lo = m1; hi = m2 - 1; }
            else hi = m1 - 1;
        }
        float fT = __uint_as_float(lo);               // exact k-th largest
        float s = 0.f, cf = 0.f;
        #pragma unroll
        for (int i = 0; i < 17; ++i)
            if (ul[i] > lo) { s += __uint_as_float(ul[i]); cf += 1.f; }
        #pragma unroll
        for (int o = 32; o > 0; o >>= 1) {
            s  += __shfl_down(s, o, 64);
            cf += __shfl_down(cf, o, 64);
        }
        if (lane == 0) { s_rf[w][0] = s; s_rf[w][1] = cf; }
        __syncthreads();
        if (w == 0) {
            float a = (lane < NWV) ? s_rf[lane][0] : 0.f;
            float bb = (lane < NWV) ? s_rf[lane][1] : 0.f;
            #pragma unroll
            for (int o = 8; o > 0; o >>= 1) {
                a  += __shfl_down(a, o, 64);
                bb += __shfl_down(bb, o, 64);
            }
            if (lane == 0) { s_ts2[0] = a; s_ts2[1] = bb; }
        }
        __syncthreads();
        topk = s_ts2[0] + ((float)k - s_ts2[1]) * fT; // ties add (k-cnt)*T
    }
    if (tid == 0) {
        float* pp = part2 + b3 * 8;
        pp[0] = t_ll; pp[1] = t_lm; pp[2] = t_lcp;
        pp[3] = topk; pp[4] = t_np; pp[5] = t_np1;
        __threadfence();
        int old = atomicAdd(done, 1);
        s_last = (old == B - 1) ? 1 : 0;
    }
    __syncthreads();
    if (s_last && w == 0) {                           // last block folds all rows
        __threadfence();
        volatile float* vp = part2;
        float ll = 0.f, lm = 0.f, lc = 0.f, tk = 0.f, np = 0.f, np1 = 0.f;
        for (int bb = lane; bb < B; bb += 64) {
            ll  += vp[bb * 8 + 0];
            lm  += vp[bb * 8 + 1];
            lc  += vp[bb * 8 + 2];
            tk  += vp[bb * 8 + 3];
            np  += vp[bb * 8 + 4];
            np1 += vp[bb * 8 + 5];
        }
        #pragma unroll
        for (int o = 32; o > 0; o >>= 1) {
            ll  += __shfl_down(ll,  o, 64);
            lm  += __shfl_down(lm,  o, 64);
            lc  += __shfl_down(lc,  o, 64);
            tk  += __shfl_down(tk,  o, 64);
            np  += __shfl_down(np,  o, 64);
            np1 += __shfl_down(np1, o, 64);
        }
        if (lane == 0) {
            float N = fmaxf(np, 1.f), N1 = fmaxf(np1, 1.f);
            out[0] = ll / N;
            out[1] = (lc + tk) / N;
            out[2] = lm / N1;
        }
    }
}

extern "C" void kernel_launch(void* const* d_in, const int* in_sizes, int n_in,
                              void* d_out, int out_size, void* d_ws, size_t ws_size,
                              hipStream_t stream) {
    const float2* cls    = (const float2*)d_in[0];
    const float4* loc    = (const float4*)d_in[1];
    const float* lmd     = (const float*)d_in[2];
    const float4* priors = (const float4*)d_in[3];
    const float* targets = (const float*)d_in[4];
    int P = in_sizes[3] / 4;            // 16800
    int B = (in_sizes[1] / 4) / P;      // 64

    size_t off = 0;
    u64* keys    = (u64*)d_ws;                     off += (size_t)B * GN * 8;
    u64* wmask   = (u64*)((char*)d_ws + off);      off += (size_t)B * NCH * NW64A * 8;
    float* pack  = (float*)((char*)d_ws + off);    off += (size_t)B * PACKF * 4;
    float* part  = (float*)((char*)d_ws + off);    off += (size_t)B * NCH * 8 * 4;
    float* part2 = (float*)((char*)d_ws + off);    off += (size_t)B * 8 * 4;
    int* done    = (int*)((char*)d_ws + off);      off += 256;
    off = (off + 255) & ~(size_t)255;
    float* bc    = (float*)((char*)d_ws + off);

    float* outp = (float*)d_out;
    void* args[] = {
        (void*)&cls, (void*)&loc, (void*)&lmd, (void*)&priors, (void*)&targets,
        (void*)&keys, (void*)&pack, (void*)&wmask, (void*)&bc, (void*)&part,
        (void*)&part2, (void*)&outp, (void*)&done, (void*)&P, (void*)&B
    };
    hipLaunchCooperativeKernel((void*)k_fused, dim3(B * NCH), dim3(NT),
                               args, 0, stream);
}